// Round 9
// baseline (235.714 us; speedup 1.0000x reference)
//
#include <hip/hip_runtime.h>
#include <cstdint>
#include <cstddef>

#define N_PIX   16384
#define K_EMB   8192
#define DDIM    256

// ws layout (bytes) — total 23,166,988 (< known-good 25,329,672)
#define WS_A8       0           // A fp8 pixel-major [16384][256]    4194304
#define WS_E8       4194304     // E fp8 (x8192) [8192][256]         2097152
#define WS_KEYS     6291456     // keys [128 halves][16384] uint2    16777216
#define WS_ZSQ      23068672    // 16384*4
#define WS_ESQ      23134208    // 8192*4
#define WS_LOSS     23166976    // 8
#define WS_CNT      23166984    // 4

typedef float f32x4 __attribute__((ext_vector_type(4)));

__device__ __forceinline__ unsigned int f32_sortable(float f) {
    unsigned int u = __float_as_uint(f);
    return (u & 0x80000000u) ? ~u : (u | 0x80000000u);
}

// fp32 -> OCP e4m3fn, round-to-nearest-even (handles subnormals; no sat needed
// for |x| <= ~5). Unbiased rounding matters: truncation would scale the dot.
__device__ __forceinline__ unsigned char f2fp8(float x) {
    unsigned ub = __float_as_uint(x);
    unsigned sgn = (ub >> 24) & 0x80u;
    unsigned b = ub & 0x7FFFFFFFu;
    unsigned out;
    if (__uint_as_float(b) < 0.015625f) {          // subnormal: step 2^-9
        out = (unsigned)(int)rintf(__uint_as_float(b) * 512.0f);  // 0..8
    } else {
        unsigned r = b + 0x7FFFFu + ((b >> 20) & 1u);   // RNE to 3 mantissa bits
        int er = (int)(r >> 23) - 127;
        out = (unsigned)(((er + 7) << 3) | ((r >> 20) & 7u));
    }
    return (unsigned char)(out | sgn);
}

__device__ __forceinline__ void async16(const unsigned char* g, unsigned char* l) {
    __builtin_amdgcn_global_load_lds(
        (const __attribute__((address_space(1))) void*)g,
        (__attribute__((address_space(3))) void*)l, 16, 0, 0);
}

// ---------------------------------------------------------------- kernel 1
// Fused prep: blocks 0..511 transpose z -> Af8 (fp8) + zsq (np pairwise);
// blocks 512..543 emb -> Ef8 (fp8 of 8192*e) + esq (np pairwise).
__global__ __launch_bounds__(256) void prep_kernel(
        const float* __restrict__ z, const float* __restrict__ emb,
        unsigned char* __restrict__ Af8, unsigned char* __restrict__ Ef8,
        float* __restrict__ zsq, float* __restrict__ esq,
        double* __restrict__ lossAcc, unsigned* __restrict__ doneCnt) {
    __shared__ float tile[32][257];
    int blk = blockIdx.x;
    int t   = threadIdx.x;
    if (blk < 512) {
        int b   = blk >> 5;
        int hw0 = (blk & 31) * 32;
        const float* zb = z + (size_t)b * 262144 + hw0;
        int px = t & 31;
        int cb = t >> 5;
#pragma unroll
        for (int cc = 0; cc < 32; ++cc) {
            int c = cc * 8 + cb;
            tile[px][c] = zb[(size_t)c * 1024 + px];
        }
        __syncthreads();
        int p0 = b * 1024 + hw0;
        int wv = t >> 6, lane = t & 63;
#pragma unroll
        for (int iter = 0; iter < 8; ++iter) {
            int pl = iter * 4 + wv;
            uchar4 o;
            o.x = f2fp8(tile[pl][lane * 4 + 0]);
            o.y = f2fp8(tile[pl][lane * 4 + 1]);
            o.z = f2fp8(tile[pl][lane * 4 + 2]);
            o.w = f2fp8(tile[pl][lane * 4 + 3]);
            ((uchar4*)(Af8 + (size_t)(p0 + pl) * 256))[lane] = o;
        }
        if (t < 32) {
            float r[16];
#pragma unroll
            for (int j = 0; j < 16; ++j) r[j] = 0.f;
#pragma unroll
            for (int c = 0; c < 256; ++c) {
                float x  = tile[t][c];
                float sq = __fmul_rn(x, x);
                int slot = ((c >> 7) << 3) | (c & 7);
                r[slot] = __fadd_rn(r[slot], sq);
            }
            float h0 = __fadd_rn(
                __fadd_rn(__fadd_rn(r[0], r[1]), __fadd_rn(r[2], r[3])),
                __fadd_rn(__fadd_rn(r[4], r[5]), __fadd_rn(r[6], r[7])));
            float h1 = __fadd_rn(
                __fadd_rn(__fadd_rn(r[8], r[9]), __fadd_rn(r[10], r[11])),
                __fadd_rn(__fadd_rn(r[12], r[13]), __fadd_rn(r[14], r[15])));
            zsq[p0 + t] = __fadd_rn(h0, h1);
        }
        if (blk == 0 && t == 0) { *lossAcc = 0.0; *doneCnt = 0u; }
    } else {
        int k = (blk - 512) * 256 + t;
        const float* ep = emb + (size_t)k * DDIM;
        uchar4* eb = (uchar4*)(Ef8 + (size_t)k * DDIM);
        float r[16];
#pragma unroll
        for (int j = 0; j < 16; ++j) r[j] = 0.f;
#pragma unroll
        for (int c4 = 0; c4 < 64; ++c4) {
            float4 v = ((const float4*)ep)[c4];
            uchar4 o;
            o.x = f2fp8(v.x * 8192.0f); o.y = f2fp8(v.y * 8192.0f);
            o.z = f2fp8(v.z * 8192.0f); o.w = f2fp8(v.w * 8192.0f);
            eb[c4] = o;
            int c = c4 * 4;
            { int slot = ((c >> 7) << 3) | (c & 7);
              r[slot] = __fadd_rn(r[slot], __fmul_rn(v.x, v.x)); }
            { int cc = c + 1; int slot = ((cc >> 7) << 3) | (cc & 7);
              r[slot] = __fadd_rn(r[slot], __fmul_rn(v.y, v.y)); }
            { int cc = c + 2; int slot = ((cc >> 7) << 3) | (cc & 7);
              r[slot] = __fadd_rn(r[slot], __fmul_rn(v.z, v.z)); }
            { int cc = c + 3; int slot = ((cc >> 7) << 3) | (cc & 7);
              r[slot] = __fadd_rn(r[slot], __fmul_rn(v.w, v.w)); }
        }
        float h0 = __fadd_rn(
            __fadd_rn(__fadd_rn(r[0], r[1]), __fadd_rn(r[2], r[3])),
            __fadd_rn(__fadd_rn(r[4], r[5]), __fadd_rn(r[6], r[7])));
        float h1 = __fadd_rn(
            __fadd_rn(__fadd_rn(r[8], r[9]), __fadd_rn(r[10], r[11])),
            __fadd_rn(__fadd_rn(r[12], r[13]), __fadd_rn(r[14], r[15])));
        esq[k] = __fadd_rn(h0, h1);
    }
}

// ---------------------------------------------------------------- kernel 2
// fp8 MFMA GEMM (R8 structure: 256 thr, 128x128 tile, BK=32, dbuf DMA).
// score_hat = esq[n] + 0.125 - dot(z8, e8)/8192*2 -> u = fmaf(acc,-512,epv).
// Top-2 per (pixel, 64-cand half) -> keys[half][p] uint2, block-major.
__global__ __launch_bounds__(256) void mfma_score_kernel(
        const unsigned char* __restrict__ Af8,
        const unsigned char* __restrict__ Ef8,
        const float* __restrict__ esq,
        unsigned int* __restrict__ keys) {
    union SM {
        struct { unsigned char As[2][4096]; unsigned char Bs[2][4096]; } k; // 16K
        struct { uint2 ep[128][33]; } e;   // 33792 B (R5-proven epilogue planes)
    };
    __shared__ SM sm;
    __shared__ float sEp[128];
    __shared__ uint2 pb[128][2];

    const int nb = blockIdx.x;     // candidate block 0..63
    const int mb = blockIdx.y;     // pixel block 0..127
    const int t = threadIdx.x;
    const int w = t >> 6, lane = t & 63;
    const int wm = w >> 1, wn = w & 1;
    const int quad = lane >> 4, l16 = lane & 15;

    if (t < 128)
        sEp[t] = (esq[nb * 128 + t] + 0.125f) * 2097152.0f;  // (esq+1/8)*2^21

    // DMA chunk map: slot t holds row rt = t>>1, k-group g = (t&1)^((rt>>2)&1)
    // (g-swizzle spreads fragment reads across bank-pairs: 2-way max = free)
    const int rt = t >> 1;
    const int gt = (t & 1) ^ ((t >> 3) & 1);
    const unsigned char* Ag = Af8 + (size_t)(mb * 128 + rt) * 256 + gt * 16;
    const unsigned char* Eg = Ef8 + (size_t)(nb * 128 + rt) * 256 + gt * 16;

    // fragment read addresses (row*32 + swizzled 16B-half + 8B quad-half)
    int aaddr[4], baddr[4];
#pragma unroll
    for (int fi = 0; fi < 4; ++fi) {
        int row = wm * 64 + fi * 16 + l16;
        int g   = (quad >> 1) ^ ((row >> 2) & 1);
        aaddr[fi] = row * 32 + g * 16 + (quad & 1) * 8;
    }
#pragma unroll
    for (int fj = 0; fj < 4; ++fj) {
        int row = wn * 64 + fj * 16 + l16;
        int g   = (quad >> 1) ^ ((row >> 2) & 1);
        baddr[fj] = row * 32 + g * 16 + (quad & 1) * 8;
    }

    f32x4 acc[4][4];
#pragma unroll
    for (int i = 0; i < 4; ++i)
#pragma unroll
        for (int j = 0; j < 4; ++j)
#pragma unroll
            for (int r = 0; r < 4; ++r) acc[i][j][r] = 0.f;

    // prologue: DMA iter 0 into buffer 0
    async16(Ag, &sm.k.As[0][t * 16]);
    async16(Eg, &sm.k.Bs[0][t * 16]);

#pragma unroll
    for (int it = 0; it < 8; ++it) {
        const int cur = it & 1, nxt = cur ^ 1;
        __syncthreads();
        if (it < 7) {
            const int k0n = (it + 1) * 32;
            async16(Ag + k0n, &sm.k.As[nxt][t * 16]);
            async16(Eg + k0n, &sm.k.Bs[nxt][t * 16]);
        }
        long long af[4], bfr[4];
#pragma unroll
        for (int fi = 0; fi < 4; ++fi)
            af[fi] = *(const long long*)&sm.k.As[cur][aaddr[fi]];
#pragma unroll
        for (int fj = 0; fj < 4; ++fj)
            bfr[fj] = *(const long long*)&sm.k.Bs[cur][baddr[fj]];
#pragma unroll
        for (int fi = 0; fi < 4; ++fi)
#pragma unroll
            for (int fj = 0; fj < 4; ++fj)
                acc[fi][fj] = __builtin_amdgcn_mfma_f32_16x16x32_fp8_fp8(
                    af[fi], bfr[fj], acc[fi][fj], 0, 0, 0);
    }

    __syncthreads();   // K-loop LDS reads done; safe to alias staging as planes

    float epv[4];
    unsigned idxc[4];
#pragma unroll
    for (int fj = 0; fj < 4; ++fj) {
        int nloc = wn * 64 + fj * 16 + l16;
        epv[fj]  = sEp[nloc];
        idxc[fj] = (unsigned)(nb * 128 + nloc);
    }

    // phase A: per (fi,r) pack 4 keys, sort4 -> top2, one ds_write_b64
#pragma unroll
    for (int fi = 0; fi < 4; ++fi) {
#pragma unroll
        for (int r = 0; r < 4; ++r) {
            unsigned kk[4];
#pragma unroll
            for (int fj = 0; fj < 4; ++fj) {
                unsigned u = (unsigned)fmaf(acc[fi][fj][r], -512.0f, epv[fj]);
                kk[fj] = (u << 13) | idxc[fj];
            }
            unsigned lo0 = min(kk[0], kk[1]), hi0 = max(kk[0], kk[1]);
            unsigned lo1 = min(kk[2], kk[3]), hi1 = max(kk[2], kk[3]);
            unsigned a0 = min(lo0, lo1);
            unsigned a1 = min(max(lo0, lo1), min(hi0, hi1));
            int row = wm * 64 + fi * 16 + quad * 4 + r;
            sm.e.ep[row][wn * 16 + l16] = make_uint2(a0, a1);
        }
    }
    __syncthreads();

    // phase B1: 2 threads per row, each scans one 64-cand half (16 entries)
    {
        int row = t >> 1, h0 = (t & 1) * 16;
        uint2 mv = sm.e.ep[row][h0];
#pragma unroll
        for (int i = 1; i < 16; ++i) {
            uint2 av = sm.e.ep[row][h0 + i];
            unsigned n0 = min(mv.x, av.x);
            unsigned n1 = min(max(mv.x, av.x), min(mv.y, av.y));
            mv.x = n0; mv.y = n1;
        }
        pb[row][t & 1] = mv;
    }
    __syncthreads();

    // phase B2: write BOTH halves' top-2, block-major (coalesced 2 KB/block)
    {
        int so = t >> 7, row = t & 127;
        ((uint2*)keys)[(size_t)(nb * 2 + so) * N_PIX + (mb * 128 + row)] =
            pb[row][so];
    }
}

// ---------------------------------------------------------------- kernel 3
// Fused: per-(b,h) block of 32 pixels — LDS z-tile, min over 128 halves'
// top-2 keys, margin candidates (ballot), exact rescore (fp64 dot -> np
// fp32), idx out, gather emb[idx] -> out, loss + last-block finalize.
__global__ __launch_bounds__(256) void final_kernel(
        const unsigned int* __restrict__ keys,
        const float* __restrict__ z, const float* __restrict__ emb,
        const float* __restrict__ zsq, const float* __restrict__ esq,
        float* __restrict__ out, float* __restrict__ idx_out,
        float* __restrict__ loss_out,
        double* __restrict__ lossAcc, unsigned* __restrict__ doneCnt) {
    __shared__ float ztile[32][260];
    __shared__ int sidx[32];
    int blk = blockIdx.x;            // 0..511
    int b = blk >> 5, h = blk & 31;
    int t = threadIdx.x;
    int p0 = b * 1024 + h * 32;
    const float* zb = z + (size_t)b * 262144 + h * 32;
    {
        int px = t & 31, cb = t >> 5;
#pragma unroll
        for (int cc = 0; cc < 32; ++cc) {
            int c = cc * 8 + cb;
            ztile[px][c] = zb[(size_t)c * 1024 + px];
        }
    }
    __syncthreads();

    int wq = t >> 6, lane = t & 63;
    const uint2* kp = (const uint2*)keys;
#pragma unroll 1
    for (int i = 0; i < 8; ++i) {
        int px = wq * 8 + i;
        int p  = p0 + px;
        // lane handles halves {lane, lane+64}; L1-reuse across the 8 pixels
        uint2 ka = kp[(size_t)lane * N_PIX + p];
        uint2 kb = kp[(size_t)(lane + 64) * N_PIX + p];
        unsigned m = min(min(ka.x, ka.y), min(kb.x, kb.y));
#pragma unroll
        for (int off = 32; off >= 1; off >>= 1)
            m = min(m, (unsigned)__shfl_xor((int)m, off, 64));
        unsigned thr = (m >> 13) + 1600;   // margin 1600*2^-21 = 7.6e-4 ~ 10σ

        float4 zv = *(const float4*)&ztile[px][lane * 4];
        float zs = zsq[p];
        unsigned long long best = ~0ull;
#pragma unroll 1
        for (int pass = 0; pass < 4; ++pass) {
            unsigned kv = (pass == 0) ? ka.x : (pass == 1) ? ka.y
                        : (pass == 2) ? kb.x : kb.y;
            unsigned long long mm = __ballot((kv >> 13) <= thr);
            while (mm) {
                int src = (int)__builtin_ctzll(mm);
                mm &= mm - 1;
                unsigned keyv = (unsigned)__shfl((int)kv, src, 64);
                int k = (int)(keyv & 0x1FFFu);
                const float4 ev = *(const float4*)(emb + (size_t)k * DDIM + lane * 4);
                double d = (double)zv.x * ev.x + (double)zv.y * ev.y
                         + (double)zv.z * ev.z + (double)zv.w * ev.w;
#pragma unroll
                for (int off = 32; off >= 1; off >>= 1)
                    d += __shfl_down(d, off, 64);
                d = __shfl(d, 0, 64);
                float df = (float)d;
                float s  = __fsub_rn(__fadd_rn(zs, esq[k]), __fmul_rn(2.0f, df));
                unsigned long long key =
                    ((unsigned long long)f32_sortable(s) << 32) | (unsigned)k;
                best = key < best ? key : best;
            }
        }
        if (lane == 0) {
            int k = (int)(unsigned)(best & 0xffffffffu);
            sidx[px] = k;
            idx_out[p] = (float)k;
        }
    }
    __syncthreads();

    // gather + loss (z from LDS)
    int wq2 = t & 31, cy = t >> 5;
    int kk = sidx[wq2];
    const float* er = emb + (size_t)kk * DDIM;
    float* ob = out + (size_t)b * 262144 + h * 32;
    float local = 0.f;
#pragma unroll 4
    for (int it = 0; it < 32; ++it) {
        int c = it * 8 + cy;
        float q = er[c];
        float d = q - ztile[wq2][c];
        ob[(size_t)c * 1024 + wq2] = q;
        local += d * d;
    }
#pragma unroll
    for (int off = 32; off >= 1; off >>= 1) local += __shfl_down(local, off, 64);
    __shared__ float wsum[4];
    if ((t & 63) == 0) wsum[t >> 6] = local;
    __syncthreads();
    if (t == 0) {
        double s = (double)wsum[0] + (double)wsum[1]
                 + (double)wsum[2] + (double)wsum[3];
        atomicAdd(lossAcc, s);
        __threadfence();
        unsigned old = atomicAdd(doneCnt, 1u);
        if (old == 511u) {
            double tot = atomicAdd(lossAcc, 0.0);  // coherent device-scope read
            *loss_out = (float)(tot * (1.25 / 4194304.0));
        }
    }
}

// ----------------------------------------------------------------
extern "C" void kernel_launch(void* const* d_in, const int* in_sizes, int n_in,
                              void* d_out, int out_size, void* d_ws, size_t ws_size,
                              hipStream_t stream) {
    const float* z   = (const float*)d_in[0];
    const float* emb = (const float*)d_in[1];
    float* out = (float*)d_out;
    char* ws = (char*)d_ws;

    unsigned char* Af8 = (unsigned char*)(ws + WS_A8);
    unsigned char* Ef8 = (unsigned char*)(ws + WS_E8);
    unsigned int* keys = (unsigned int*)(ws + WS_KEYS);
    float* zsq      = (float*)(ws + WS_ZSQ);
    float* esq      = (float*)(ws + WS_ESQ);
    double* lossAcc = (double*)(ws + WS_LOSS);
    unsigned* doneCnt = (unsigned*)(ws + WS_CNT);

    prep_kernel<<<544, 256, 0, stream>>>(z, emb, Af8, Ef8, zsq, esq,
                                         lossAcc, doneCnt);
    mfma_score_kernel<<<dim3(64, 128), 256, 0, stream>>>(Af8, Ef8, esq, keys);
    final_kernel<<<512, 256, 0, stream>>>(keys, z, emb, zsq, esq,
                                          out, out + 4194305, out + 4194304,
                                          lossAcc, doneCnt);
}

// Round 10
// 224.079 us; speedup vs baseline: 1.0519x; 1.0519x over previous
//
#include <hip/hip_runtime.h>
#include <cstdint>
#include <cstddef>

#define N_PIX   16384
#define K_EMB   8192
#define DDIM    256

// ws layout (bytes) — total 23,166,988
#define WS_A8       0           // A fp8 pixel-major [16384][256]    4194304
#define WS_E8       4194304     // E fp8 (x8192) [8192][256]         2097152
#define WS_KEYS     6291456     // keys [128 halves][16384] uint2    16777216
#define WS_ZSQ      23068672    // 16384*4
#define WS_ESQ      23134208    // 8192*4
#define WS_LOSS     23166976    // 8
#define WS_CNT      23166984    // 4

typedef float f32x4 __attribute__((ext_vector_type(4)));

__device__ __forceinline__ unsigned int f32_sortable(float f) {
    unsigned int u = __float_as_uint(f);
    return (u & 0x80000000u) ? ~u : (u | 0x80000000u);
}

// fp32 -> OCP e4m3fn RNE (fallback path; handles subnormals)
__device__ __forceinline__ unsigned char f2fp8(float x) {
    unsigned ub = __float_as_uint(x);
    unsigned sgn = (ub >> 24) & 0x80u;
    unsigned b = ub & 0x7FFFFFFFu;
    unsigned out;
    if (__uint_as_float(b) < 0.015625f) {
        out = (unsigned)(int)rintf(__uint_as_float(b) * 512.0f);
    } else {
        unsigned r = b + 0x7FFFFu + ((b >> 20) & 1u);
        int er = (int)(r >> 23) - 127;
        out = (unsigned)(((er + 7) << 3) | ((r >> 20) & 7u));
    }
    return (unsigned char)(out | sgn);
}

#if defined(__has_builtin)
#if __has_builtin(__builtin_amdgcn_cvt_pk_fp8_f32)
#define HAVE_CVT_FP8 1
#endif
#endif

// pack 4 fp32 -> 4 fp8 bytes (one dword); HW convert when available
__device__ __forceinline__ unsigned pack4_fp8(float a, float b, float c, float d) {
#ifdef HAVE_CVT_FP8
    int pk = 0;
    pk = __builtin_amdgcn_cvt_pk_fp8_f32(a, b, pk, false);  // bytes 0,1
    pk = __builtin_amdgcn_cvt_pk_fp8_f32(c, d, pk, true);   // bytes 2,3
    return (unsigned)pk;
#else
    return (unsigned)f2fp8(a) | ((unsigned)f2fp8(b) << 8)
         | ((unsigned)f2fp8(c) << 16) | ((unsigned)f2fp8(d) << 24);
#endif
}

__device__ __forceinline__ void async16(const unsigned char* g, unsigned char* l) {
    __builtin_amdgcn_global_load_lds(
        (const __attribute__((address_space(1))) void*)g,
        (__attribute__((address_space(3))) void*)l, 16, 0, 0);
}

// ---------------------------------------------------------------- kernel 1
// Fused prep: blocks 0..511 transpose z -> Af8 (fp8) + zsq (np pairwise);
// blocks 512..543 emb -> Ef8 (fp8 of 8192*e) + esq (np pairwise).
__global__ __launch_bounds__(256) void prep_kernel(
        const float* __restrict__ z, const float* __restrict__ emb,
        unsigned char* __restrict__ Af8, unsigned char* __restrict__ Ef8,
        float* __restrict__ zsq, float* __restrict__ esq,
        double* __restrict__ lossAcc, unsigned* __restrict__ doneCnt) {
    __shared__ float tile[32][257];
    int blk = blockIdx.x;
    int t   = threadIdx.x;
    if (blk < 512) {
        int b   = blk >> 5;
        int hw0 = (blk & 31) * 32;
        const float* zb = z + (size_t)b * 262144 + hw0;
        int px = t & 31;
        int cb = t >> 5;
#pragma unroll
        for (int cc = 0; cc < 32; ++cc) {
            int c = cc * 8 + cb;
            tile[px][c] = zb[(size_t)c * 1024 + px];
        }
        __syncthreads();
        int p0 = b * 1024 + hw0;
        int wv = t >> 6, lane = t & 63;
#pragma unroll
        for (int iter = 0; iter < 8; ++iter) {
            int pl = iter * 4 + wv;
            unsigned pk = pack4_fp8(tile[pl][lane * 4 + 0], tile[pl][lane * 4 + 1],
                                    tile[pl][lane * 4 + 2], tile[pl][lane * 4 + 3]);
            ((unsigned*)(Af8 + (size_t)(p0 + pl) * 256))[lane] = pk;
        }
        if (t < 32) {
            float r[16];
#pragma unroll
            for (int j = 0; j < 16; ++j) r[j] = 0.f;
#pragma unroll
            for (int c = 0; c < 256; ++c) {
                float x  = tile[t][c];
                float sq = __fmul_rn(x, x);
                int slot = ((c >> 7) << 3) | (c & 7);
                r[slot] = __fadd_rn(r[slot], sq);
            }
            float h0 = __fadd_rn(
                __fadd_rn(__fadd_rn(r[0], r[1]), __fadd_rn(r[2], r[3])),
                __fadd_rn(__fadd_rn(r[4], r[5]), __fadd_rn(r[6], r[7])));
            float h1 = __fadd_rn(
                __fadd_rn(__fadd_rn(r[8], r[9]), __fadd_rn(r[10], r[11])),
                __fadd_rn(__fadd_rn(r[12], r[13]), __fadd_rn(r[14], r[15])));
            zsq[p0 + t] = __fadd_rn(h0, h1);
        }
        if (blk == 0 && t == 0) { *lossAcc = 0.0; *doneCnt = 0u; }
    } else {
        int k = (blk - 512) * 256 + t;
        const float* ep = emb + (size_t)k * DDIM;
        unsigned* eb = (unsigned*)(Ef8 + (size_t)k * DDIM);
        float r[16];
#pragma unroll
        for (int j = 0; j < 16; ++j) r[j] = 0.f;
#pragma unroll
        for (int c4 = 0; c4 < 64; ++c4) {
            float4 v = ((const float4*)ep)[c4];
            eb[c4] = pack4_fp8(v.x * 8192.0f, v.y * 8192.0f,
                               v.z * 8192.0f, v.w * 8192.0f);
            int c = c4 * 4;
            { int slot = ((c >> 7) << 3) | (c & 7);
              r[slot] = __fadd_rn(r[slot], __fmul_rn(v.x, v.x)); }
            { int cc = c + 1; int slot = ((cc >> 7) << 3) | (cc & 7);
              r[slot] = __fadd_rn(r[slot], __fmul_rn(v.y, v.y)); }
            { int cc = c + 2; int slot = ((cc >> 7) << 3) | (cc & 7);
              r[slot] = __fadd_rn(r[slot], __fmul_rn(v.z, v.z)); }
            { int cc = c + 3; int slot = ((cc >> 7) << 3) | (cc & 7);
              r[slot] = __fadd_rn(r[slot], __fmul_rn(v.w, v.w)); }
        }
        float h0 = __fadd_rn(
            __fadd_rn(__fadd_rn(r[0], r[1]), __fadd_rn(r[2], r[3])),
            __fadd_rn(__fadd_rn(r[4], r[5]), __fadd_rn(r[6], r[7])));
        float h1 = __fadd_rn(
            __fadd_rn(__fadd_rn(r[8], r[9]), __fadd_rn(r[10], r[11])),
            __fadd_rn(__fadd_rn(r[12], r[13]), __fadd_rn(r[14], r[15])));
        esq[k] = __fadd_rn(h0, h1);
    }
}

// ---------------------------------------------------------------- kernel 2
// fp8 MFMA GEMM — unchanged from R9 (measured 86 us).
__global__ __launch_bounds__(256) void mfma_score_kernel(
        const unsigned char* __restrict__ Af8,
        const unsigned char* __restrict__ Ef8,
        const float* __restrict__ esq,
        unsigned int* __restrict__ keys) {
    union SM {
        struct { unsigned char As[2][4096]; unsigned char Bs[2][4096]; } k;
        struct { uint2 ep[128][33]; } e;
    };
    __shared__ SM sm;
    __shared__ float sEp[128];
    __shared__ uint2 pb[128][2];

    const int nb = blockIdx.x;
    const int mb = blockIdx.y;
    const int t = threadIdx.x;
    const int w = t >> 6, lane = t & 63;
    const int wm = w >> 1, wn = w & 1;
    const int quad = lane >> 4, l16 = lane & 15;

    if (t < 128)
        sEp[t] = (esq[nb * 128 + t] + 0.125f) * 2097152.0f;

    const int rt = t >> 1;
    const int gt = (t & 1) ^ ((t >> 3) & 1);
    const unsigned char* Ag = Af8 + (size_t)(mb * 128 + rt) * 256 + gt * 16;
    const unsigned char* Eg = Ef8 + (size_t)(nb * 128 + rt) * 256 + gt * 16;

    int aaddr[4], baddr[4];
#pragma unroll
    for (int fi = 0; fi < 4; ++fi) {
        int row = wm * 64 + fi * 16 + l16;
        int g   = (quad >> 1) ^ ((row >> 2) & 1);
        aaddr[fi] = row * 32 + g * 16 + (quad & 1) * 8;
    }
#pragma unroll
    for (int fj = 0; fj < 4; ++fj) {
        int row = wn * 64 + fj * 16 + l16;
        int g   = (quad >> 1) ^ ((row >> 2) & 1);
        baddr[fj] = row * 32 + g * 16 + (quad & 1) * 8;
    }

    f32x4 acc[4][4];
#pragma unroll
    for (int i = 0; i < 4; ++i)
#pragma unroll
        for (int j = 0; j < 4; ++j)
#pragma unroll
            for (int r = 0; r < 4; ++r) acc[i][j][r] = 0.f;

    async16(Ag, &sm.k.As[0][t * 16]);
    async16(Eg, &sm.k.Bs[0][t * 16]);

#pragma unroll
    for (int it = 0; it < 8; ++it) {
        const int cur = it & 1, nxt = cur ^ 1;
        __syncthreads();
        if (it < 7) {
            const int k0n = (it + 1) * 32;
            async16(Ag + k0n, &sm.k.As[nxt][t * 16]);
            async16(Eg + k0n, &sm.k.Bs[nxt][t * 16]);
        }
        long long af[4], bfr[4];
#pragma unroll
        for (int fi = 0; fi < 4; ++fi)
            af[fi] = *(const long long*)&sm.k.As[cur][aaddr[fi]];
#pragma unroll
        for (int fj = 0; fj < 4; ++fj)
            bfr[fj] = *(const long long*)&sm.k.Bs[cur][baddr[fj]];
#pragma unroll
        for (int fi = 0; fi < 4; ++fi)
#pragma unroll
            for (int fj = 0; fj < 4; ++fj)
                acc[fi][fj] = __builtin_amdgcn_mfma_f32_16x16x32_fp8_fp8(
                    af[fi], bfr[fj], acc[fi][fj], 0, 0, 0);
    }

    __syncthreads();

    float epv[4];
    unsigned idxc[4];
#pragma unroll
    for (int fj = 0; fj < 4; ++fj) {
        int nloc = wn * 64 + fj * 16 + l16;
        epv[fj]  = sEp[nloc];
        idxc[fj] = (unsigned)(nb * 128 + nloc);
    }

#pragma unroll
    for (int fi = 0; fi < 4; ++fi) {
#pragma unroll
        for (int r = 0; r < 4; ++r) {
            unsigned kk[4];
#pragma unroll
            for (int fj = 0; fj < 4; ++fj) {
                unsigned u = (unsigned)fmaf(acc[fi][fj][r], -512.0f, epv[fj]);
                kk[fj] = (u << 13) | idxc[fj];
            }
            unsigned lo0 = min(kk[0], kk[1]), hi0 = max(kk[0], kk[1]);
            unsigned lo1 = min(kk[2], kk[3]), hi1 = max(kk[2], kk[3]);
            unsigned a0 = min(lo0, lo1);
            unsigned a1 = min(max(lo0, lo1), min(hi0, hi1));
            int row = wm * 64 + fi * 16 + quad * 4 + r;
            sm.e.ep[row][wn * 16 + l16] = make_uint2(a0, a1);
        }
    }
    __syncthreads();

    {
        int row = t >> 1, h0 = (t & 1) * 16;
        uint2 mv = sm.e.ep[row][h0];
#pragma unroll
        for (int i = 1; i < 16; ++i) {
            uint2 av = sm.e.ep[row][h0 + i];
            unsigned n0 = min(mv.x, av.x);
            unsigned n1 = min(max(mv.x, av.x), min(mv.y, av.y));
            mv.x = n0; mv.y = n1;
        }
        pb[row][t & 1] = mv;
    }
    __syncthreads();

    {
        int so = t >> 7, row = t & 127;
        ((uint2*)keys)[(size_t)(nb * 2 + so) * N_PIX + (mb * 128 + row)] =
            pb[row][so];
    }
}

// ---------------------------------------------------------------- kernel 3
// Fused final, 1024 blocks x 16 pixels: coalesced LDS staging of keys
// (transpose in LDS), ballot-driven exact rescore, gather + loss.
__global__ __launch_bounds__(256) void final_kernel(
        const unsigned int* __restrict__ keys,
        const float* __restrict__ z, const float* __restrict__ emb,
        const float* __restrict__ zsq, const float* __restrict__ esq,
        float* __restrict__ out, float* __restrict__ idx_out,
        float* __restrict__ loss_out,
        double* __restrict__ lossAcc, unsigned* __restrict__ doneCnt) {
    __shared__ float ztile[16][260];
    __shared__ uint2 kt[16][129];        // [pixel][half] — ballot reads stride-2 words
    __shared__ int sidx[16];
    int blk = blockIdx.x;                // 0..1023 = b*64 + hh
    int b = blk >> 6, hh = blk & 63;
    int t = threadIdx.x;
    int p0 = b * 1024 + hh * 16;
    const float* zb = z + (size_t)b * 262144 + hh * 16;
    {
        int px = t & 15, cb = t >> 4;    // cb 0..15
#pragma unroll
        for (int cc = 0; cc < 16; ++cc) {
            int c = cc * 16 + cb;
            ztile[px][c] = zb[(size_t)c * 1024 + px];
        }
    }
    // stage keys: 16 px x 128 halves, coalesced 128B segments per half
    {
        const uint2* kg = (const uint2*)keys;
#pragma unroll
        for (int itr = 0; itr < 8; ++itr) {
            int idx = itr * 256 + t;     // 0..2047
            int px = idx & 15, hf = idx >> 4;
            kt[px][hf] = kg[(size_t)hf * N_PIX + p0 + px];
        }
    }
    __syncthreads();

    int wq = t >> 6, lane = t & 63;
#pragma unroll 1
    for (int i = 0; i < 4; ++i) {
        int px = wq * 4 + i;
        int p  = p0 + px;
        uint2 ka = kt[px][lane];
        uint2 kb = kt[px][lane + 64];
        unsigned m = min(min(ka.x, ka.y), min(kb.x, kb.y));
#pragma unroll
        for (int off = 32; off >= 1; off >>= 1)
            m = min(m, (unsigned)__shfl_xor((int)m, off, 64));
        unsigned thr = (m >> 13) + 1600;   // margin 1600*2^-21 = 7.6e-4 ~ 10σ

        float4 zv = *(const float4*)&ztile[px][lane * 4];
        float zs = zsq[p];
        unsigned long long best = ~0ull;
#pragma unroll 1
        for (int pass = 0; pass < 4; ++pass) {
            unsigned kv = (pass == 0) ? ka.x : (pass == 1) ? ka.y
                        : (pass == 2) ? kb.x : kb.y;
            unsigned long long mm = __ballot((kv >> 13) <= thr);
            while (mm) {
                int src = (int)__builtin_ctzll(mm);
                mm &= mm - 1;
                unsigned keyv = (unsigned)__shfl((int)kv, src, 64);
                int k = (int)(keyv & 0x1FFFu);
                const float4 ev = *(const float4*)(emb + (size_t)k * DDIM + lane * 4);
                double d = (double)zv.x * ev.x + (double)zv.y * ev.y
                         + (double)zv.z * ev.z + (double)zv.w * ev.w;
#pragma unroll
                for (int off = 32; off >= 1; off >>= 1)
                    d += __shfl_down(d, off, 64);
                d = __shfl(d, 0, 64);
                float df = (float)d;
                float s  = __fsub_rn(__fadd_rn(zs, esq[k]), __fmul_rn(2.0f, df));
                unsigned long long key =
                    ((unsigned long long)f32_sortable(s) << 32) | (unsigned)k;
                best = key < best ? key : best;
            }
        }
        if (lane == 0) {
            int k = (int)(unsigned)(best & 0xffffffffu);
            sidx[px] = k;
            idx_out[p] = (float)k;
        }
    }
    __syncthreads();

    // gather + loss (z from LDS)
    int px2 = t & 15, cy = t >> 4;       // cy 0..15
    int kk = sidx[px2];
    const float* er = emb + (size_t)kk * DDIM;
    float* ob = out + (size_t)b * 262144 + hh * 16;
    float local = 0.f;
#pragma unroll 4
    for (int it = 0; it < 16; ++it) {
        int c = it * 16 + cy;
        float q = er[c];
        float d = q - ztile[px2][c];
        ob[(size_t)c * 1024 + px2] = q;
        local += d * d;
    }
#pragma unroll
    for (int off = 32; off >= 1; off >>= 1) local += __shfl_down(local, off, 64);
    __shared__ float wsum[4];
    if ((t & 63) == 0) wsum[t >> 6] = local;
    __syncthreads();
    if (t == 0) {
        double s = (double)wsum[0] + (double)wsum[1]
                 + (double)wsum[2] + (double)wsum[3];
        atomicAdd(lossAcc, s);
        __threadfence();
        unsigned old = atomicAdd(doneCnt, 1u);
        if (old == 1023u) {
            double tot = atomicAdd(lossAcc, 0.0);  // coherent device-scope read
            *loss_out = (float)(tot * (1.25 / 4194304.0));
        }
    }
}

// ----------------------------------------------------------------
extern "C" void kernel_launch(void* const* d_in, const int* in_sizes, int n_in,
                              void* d_out, int out_size, void* d_ws, size_t ws_size,
                              hipStream_t stream) {
    const float* z   = (const float*)d_in[0];
    const float* emb = (const float*)d_in[1];
    float* out = (float*)d_out;
    char* ws = (char*)d_ws;

    unsigned char* Af8 = (unsigned char*)(ws + WS_A8);
    unsigned char* Ef8 = (unsigned char*)(ws + WS_E8);
    unsigned int* keys = (unsigned int*)(ws + WS_KEYS);
    float* zsq      = (float*)(ws + WS_ZSQ);
    float* esq      = (float*)(ws + WS_ESQ);
    double* lossAcc = (double*)(ws + WS_LOSS);
    unsigned* doneCnt = (unsigned*)(ws + WS_CNT);

    prep_kernel<<<544, 256, 0, stream>>>(z, emb, Af8, Ef8, zsq, esq,
                                         lossAcc, doneCnt);
    mfma_score_kernel<<<dim3(64, 128), 256, 0, stream>>>(Af8, Ef8, esq, keys);
    final_kernel<<<1024, 256, 0, stream>>>(keys, z, emb, zsq, esq,
                                           out, out + 4194305, out + 4194304,
                                           lossAcc, doneCnt);
}

// Round 11
// 215.510 us; speedup vs baseline: 1.0937x; 1.0398x over previous
//
#include <hip/hip_runtime.h>
#include <cstdint>
#include <cstddef>

#define N_PIX   16384
#define K_EMB   8192
#define DDIM    256

// ws layout (bytes) — total 23,166,988
#define WS_A8       0           // A fp8 pixel-major [16384][256]    4194304
#define WS_E8       4194304     // E fp8 (x8192) [8192][256]         2097152
#define WS_KEYS     6291456     // keys [128 halves][16384] uint2    16777216
#define WS_ZSQ      23068672    // 16384*4
#define WS_ESQ      23134208    // 8192*4
#define WS_LOSS     23166976    // 8
#define WS_CNT      23166984    // 4

typedef float f32x4 __attribute__((ext_vector_type(4)));

__device__ __forceinline__ unsigned int f32_sortable(float f) {
    unsigned int u = __float_as_uint(f);
    return (u & 0x80000000u) ? ~u : (u | 0x80000000u);
}

// fp32 -> OCP e4m3fn RNE (fallback path; handles subnormals)
__device__ __forceinline__ unsigned char f2fp8(float x) {
    unsigned ub = __float_as_uint(x);
    unsigned sgn = (ub >> 24) & 0x80u;
    unsigned b = ub & 0x7FFFFFFFu;
    unsigned out;
    if (__uint_as_float(b) < 0.015625f) {
        out = (unsigned)(int)rintf(__uint_as_float(b) * 512.0f);
    } else {
        unsigned r = b + 0x7FFFFu + ((b >> 20) & 1u);
        int er = (int)(r >> 23) - 127;
        out = (unsigned)(((er + 7) << 3) | ((r >> 20) & 7u));
    }
    return (unsigned char)(out | sgn);
}

#if defined(__has_builtin)
#if __has_builtin(__builtin_amdgcn_cvt_pk_fp8_f32)
#define HAVE_CVT_FP8 1
#endif
#endif

// pack 4 fp32 -> 4 fp8 bytes (one dword); HW convert when available
__device__ __forceinline__ unsigned pack4_fp8(float a, float b, float c, float d) {
#ifdef HAVE_CVT_FP8
    int pk = 0;
    pk = __builtin_amdgcn_cvt_pk_fp8_f32(a, b, pk, false);  // bytes 0,1
    pk = __builtin_amdgcn_cvt_pk_fp8_f32(c, d, pk, true);   // bytes 2,3
    return (unsigned)pk;
#else
    return (unsigned)f2fp8(a) | ((unsigned)f2fp8(b) << 8)
         | ((unsigned)f2fp8(c) << 16) | ((unsigned)f2fp8(d) << 24);
#endif
}

__device__ __forceinline__ void async16(const unsigned char* g, unsigned char* l) {
    __builtin_amdgcn_global_load_lds(
        (const __attribute__((address_space(1))) void*)g,
        (__attribute__((address_space(3))) void*)l, 16, 0, 0);
}

// np pairwise-sum of squares over 256 contiguous LDS floats (one thread)
__device__ __forceinline__ float np_pairwise_sq256(const float* row) {
    float r[16];
#pragma unroll
    for (int j = 0; j < 16; ++j) r[j] = 0.f;
#pragma unroll
    for (int c = 0; c < 256; ++c) {
        float x  = row[c];
        float sq = __fmul_rn(x, x);
        int slot = ((c >> 7) << 3) | (c & 7);
        r[slot] = __fadd_rn(r[slot], sq);
    }
    float h0 = __fadd_rn(
        __fadd_rn(__fadd_rn(r[0], r[1]), __fadd_rn(r[2], r[3])),
        __fadd_rn(__fadd_rn(r[4], r[5]), __fadd_rn(r[6], r[7])));
    float h1 = __fadd_rn(
        __fadd_rn(__fadd_rn(r[8], r[9]), __fadd_rn(r[10], r[11])),
        __fadd_rn(__fadd_rn(r[12], r[13]), __fadd_rn(r[14], r[15])));
    return __fadd_rn(h0, h1);
}

// ---------------------------------------------------------------- kernel 1
// Fused prep: blocks 0..511 transpose z -> Af8 (fp8) + zsq (np pairwise);
// blocks 512..767 LDS-staged emb -> Ef8 (fp8 of 8192*e) + esq (np pairwise),
// 32 rows/block, fully coalesced (fixes the R4-R10 uncoalesced esq branch).
__global__ __launch_bounds__(256) void prep_kernel(
        const float* __restrict__ z, const float* __restrict__ emb,
        unsigned char* __restrict__ Af8, unsigned char* __restrict__ Ef8,
        float* __restrict__ zsq, float* __restrict__ esq,
        double* __restrict__ lossAcc, unsigned* __restrict__ doneCnt) {
    __shared__ float tile[32][257];
    int blk = blockIdx.x;
    int t   = threadIdx.x;
    if (blk < 512) {
        int b   = blk >> 5;
        int hw0 = (blk & 31) * 32;
        const float* zb = z + (size_t)b * 262144 + hw0;
        int px = t & 31;
        int cb = t >> 5;
#pragma unroll
        for (int cc = 0; cc < 32; ++cc) {
            int c = cc * 8 + cb;
            tile[px][c] = zb[(size_t)c * 1024 + px];
        }
        __syncthreads();
        int p0 = b * 1024 + hw0;
        int wv = t >> 6, lane = t & 63;
#pragma unroll
        for (int iter = 0; iter < 8; ++iter) {
            int pl = iter * 4 + wv;
            unsigned pk = pack4_fp8(tile[pl][lane * 4 + 0], tile[pl][lane * 4 + 1],
                                    tile[pl][lane * 4 + 2], tile[pl][lane * 4 + 3]);
            ((unsigned*)(Af8 + (size_t)(p0 + pl) * 256))[lane] = pk;
        }
        if (t < 32) zsq[p0 + t] = np_pairwise_sq256(tile[t]);
        if (blk == 0 && t == 0) { *lossAcc = 0.0; *doneCnt = 0u; }
    } else {
        // emb branch: 32 rows per block, coalesced via LDS staging
        int k0 = (blk - 512) * 32;
        const float4* eg = (const float4*)(emb + (size_t)k0 * DDIM);
#pragma unroll
        for (int i = 0; i < 8; ++i) {
            int idx = i * 256 + t;         // 0..2047 float4s
            int row = idx >> 6, c4 = idx & 63;
            float4 v = eg[idx];
            *(float4*)&tile[row][c4 * 4] = v;
        }
        __syncthreads();
#pragma unroll
        for (int i = 0; i < 8; ++i) {
            int idx = i * 256 + t;
            int row = idx >> 6, c4 = idx & 63;
            const float* rp = &tile[row][c4 * 4];
            ((unsigned*)(Ef8 + (size_t)(k0 + row) * 256))[c4] =
                pack4_fp8(rp[0] * 8192.0f, rp[1] * 8192.0f,
                          rp[2] * 8192.0f, rp[3] * 8192.0f);
        }
        if (t < 32) esq[k0 + t] = np_pairwise_sq256(tile[t]);
    }
}

// ---------------------------------------------------------------- kernel 2
// fp8 MFMA GEMM — unchanged from R9/R10 (measured 84-86 us).
__global__ __launch_bounds__(256) void mfma_score_kernel(
        const unsigned char* __restrict__ Af8,
        const unsigned char* __restrict__ Ef8,
        const float* __restrict__ esq,
        unsigned int* __restrict__ keys) {
    union SM {
        struct { unsigned char As[2][4096]; unsigned char Bs[2][4096]; } k;
        struct { uint2 ep[128][33]; } e;
    };
    __shared__ SM sm;
    __shared__ float sEp[128];
    __shared__ uint2 pb[128][2];

    const int nb = blockIdx.x;
    const int mb = blockIdx.y;
    const int t = threadIdx.x;
    const int w = t >> 6, lane = t & 63;
    const int wm = w >> 1, wn = w & 1;
    const int quad = lane >> 4, l16 = lane & 15;

    if (t < 128)
        sEp[t] = (esq[nb * 128 + t] + 0.125f) * 2097152.0f;

    const int rt = t >> 1;
    const int gt = (t & 1) ^ ((t >> 3) & 1);
    const unsigned char* Ag = Af8 + (size_t)(mb * 128 + rt) * 256 + gt * 16;
    const unsigned char* Eg = Ef8 + (size_t)(nb * 128 + rt) * 256 + gt * 16;

    int aaddr[4], baddr[4];
#pragma unroll
    for (int fi = 0; fi < 4; ++fi) {
        int row = wm * 64 + fi * 16 + l16;
        int g   = (quad >> 1) ^ ((row >> 2) & 1);
        aaddr[fi] = row * 32 + g * 16 + (quad & 1) * 8;
    }
#pragma unroll
    for (int fj = 0; fj < 4; ++fj) {
        int row = wn * 64 + fj * 16 + l16;
        int g   = (quad >> 1) ^ ((row >> 2) & 1);
        baddr[fj] = row * 32 + g * 16 + (quad & 1) * 8;
    }

    f32x4 acc[4][4];
#pragma unroll
    for (int i = 0; i < 4; ++i)
#pragma unroll
        for (int j = 0; j < 4; ++j)
#pragma unroll
            for (int r = 0; r < 4; ++r) acc[i][j][r] = 0.f;

    async16(Ag, &sm.k.As[0][t * 16]);
    async16(Eg, &sm.k.Bs[0][t * 16]);

#pragma unroll
    for (int it = 0; it < 8; ++it) {
        const int cur = it & 1, nxt = cur ^ 1;
        __syncthreads();
        if (it < 7) {
            const int k0n = (it + 1) * 32;
            async16(Ag + k0n, &sm.k.As[nxt][t * 16]);
            async16(Eg + k0n, &sm.k.Bs[nxt][t * 16]);
        }
        long long af[4], bfr[4];
#pragma unroll
        for (int fi = 0; fi < 4; ++fi)
            af[fi] = *(const long long*)&sm.k.As[cur][aaddr[fi]];
#pragma unroll
        for (int fj = 0; fj < 4; ++fj)
            bfr[fj] = *(const long long*)&sm.k.Bs[cur][baddr[fj]];
#pragma unroll
        for (int fi = 0; fi < 4; ++fi)
#pragma unroll
            for (int fj = 0; fj < 4; ++fj)
                acc[fi][fj] = __builtin_amdgcn_mfma_f32_16x16x32_fp8_fp8(
                    af[fi], bfr[fj], acc[fi][fj], 0, 0, 0);
    }

    __syncthreads();

    float epv[4];
    unsigned idxc[4];
#pragma unroll
    for (int fj = 0; fj < 4; ++fj) {
        int nloc = wn * 64 + fj * 16 + l16;
        epv[fj]  = sEp[nloc];
        idxc[fj] = (unsigned)(nb * 128 + nloc);
    }

#pragma unroll
    for (int fi = 0; fi < 4; ++fi) {
#pragma unroll
        for (int r = 0; r < 4; ++r) {
            unsigned kk[4];
#pragma unroll
            for (int fj = 0; fj < 4; ++fj) {
                unsigned u = (unsigned)fmaf(acc[fi][fj][r], -512.0f, epv[fj]);
                kk[fj] = (u << 13) | idxc[fj];
            }
            unsigned lo0 = min(kk[0], kk[1]), hi0 = max(kk[0], kk[1]);
            unsigned lo1 = min(kk[2], kk[3]), hi1 = max(kk[2], kk[3]);
            unsigned a0 = min(lo0, lo1);
            unsigned a1 = min(max(lo0, lo1), min(hi0, hi1));
            int row = wm * 64 + fi * 16 + quad * 4 + r;
            sm.e.ep[row][wn * 16 + l16] = make_uint2(a0, a1);
        }
    }
    __syncthreads();

    {
        int row = t >> 1, h0 = (t & 1) * 16;
        uint2 mv = sm.e.ep[row][h0];
#pragma unroll
        for (int i = 1; i < 16; ++i) {
            uint2 av = sm.e.ep[row][h0 + i];
            unsigned n0 = min(mv.x, av.x);
            unsigned n1 = min(max(mv.x, av.x), min(mv.y, av.y));
            mv.x = n0; mv.y = n1;
        }
        pb[row][t & 1] = mv;
    }
    __syncthreads();

    {
        int so = t >> 7, row = t & 127;
        ((uint2*)keys)[(size_t)(nb * 2 + so) * N_PIX + (mb * 128 + row)] =
            pb[row][so];
    }
}

// ---------------------------------------------------------------- kernel 3
// Fused final (unchanged from R10): 1024 blocks x 16 pixels, coalesced LDS
// staging of keys, ballot-driven exact rescore, gather + loss + finalize.
__global__ __launch_bounds__(256) void final_kernel(
        const unsigned int* __restrict__ keys,
        const float* __restrict__ z, const float* __restrict__ emb,
        const float* __restrict__ zsq, const float* __restrict__ esq,
        float* __restrict__ out, float* __restrict__ idx_out,
        float* __restrict__ loss_out,
        double* __restrict__ lossAcc, unsigned* __restrict__ doneCnt) {
    __shared__ float ztile[16][260];
    __shared__ uint2 kt[16][129];
    __shared__ int sidx[16];
    int blk = blockIdx.x;                // 0..1023 = b*64 + hh
    int b = blk >> 6, hh = blk & 63;
    int t = threadIdx.x;
    int p0 = b * 1024 + hh * 16;
    const float* zb = z + (size_t)b * 262144 + hh * 16;
    {
        int px = t & 15, cb = t >> 4;
#pragma unroll
        for (int cc = 0; cc < 16; ++cc) {
            int c = cc * 16 + cb;
            ztile[px][c] = zb[(size_t)c * 1024 + px];
        }
    }
    {
        const uint2* kg = (const uint2*)keys;
#pragma unroll
        for (int itr = 0; itr < 8; ++itr) {
            int idx = itr * 256 + t;
            int px = idx & 15, hf = idx >> 4;
            kt[px][hf] = kg[(size_t)hf * N_PIX + p0 + px];
        }
    }
    __syncthreads();

    int wq = t >> 6, lane = t & 63;
#pragma unroll 1
    for (int i = 0; i < 4; ++i) {
        int px = wq * 4 + i;
        int p  = p0 + px;
        uint2 ka = kt[px][lane];
        uint2 kb = kt[px][lane + 64];
        unsigned m = min(min(ka.x, ka.y), min(kb.x, kb.y));
#pragma unroll
        for (int off = 32; off >= 1; off >>= 1)
            m = min(m, (unsigned)__shfl_xor((int)m, off, 64));
        unsigned thr = (m >> 13) + 1600;   // margin 1600*2^-21 = 7.6e-4

        float4 zv = *(const float4*)&ztile[px][lane * 4];
        float zs = zsq[p];
        unsigned long long best = ~0ull;
#pragma unroll 1
        for (int pass = 0; pass < 4; ++pass) {
            unsigned kv = (pass == 0) ? ka.x : (pass == 1) ? ka.y
                        : (pass == 2) ? kb.x : kb.y;
            unsigned long long mm = __ballot((kv >> 13) <= thr);
            while (mm) {
                int src = (int)__builtin_ctzll(mm);
                mm &= mm - 1;
                unsigned keyv = (unsigned)__shfl((int)kv, src, 64);
                int k = (int)(keyv & 0x1FFFu);
                const float4 ev = *(const float4*)(emb + (size_t)k * DDIM + lane * 4);
                double d = (double)zv.x * ev.x + (double)zv.y * ev.y
                         + (double)zv.z * ev.z + (double)zv.w * ev.w;
#pragma unroll
                for (int off = 32; off >= 1; off >>= 1)
                    d += __shfl_down(d, off, 64);
                d = __shfl(d, 0, 64);
                float df = (float)d;
                float s  = __fsub_rn(__fadd_rn(zs, esq[k]), __fmul_rn(2.0f, df));
                unsigned long long key =
                    ((unsigned long long)f32_sortable(s) << 32) | (unsigned)k;
                best = key < best ? key : best;
            }
        }
        if (lane == 0) {
            int k = (int)(unsigned)(best & 0xffffffffu);
            sidx[px] = k;
            idx_out[p] = (float)k;
        }
    }
    __syncthreads();

    int px2 = t & 15, cy = t >> 4;
    int kk = sidx[px2];
    const float* er = emb + (size_t)kk * DDIM;
    float* ob = out + (size_t)b * 262144 + hh * 16;
    float local = 0.f;
#pragma unroll 4
    for (int it = 0; it < 16; ++it) {
        int c = it * 16 + cy;
        float q = er[c];
        float d = q - ztile[px2][c];
        ob[(size_t)c * 1024 + px2] = q;
        local += d * d;
    }
#pragma unroll
    for (int off = 32; off >= 1; off >>= 1) local += __shfl_down(local, off, 64);
    __shared__ float wsum[4];
    if ((t & 63) == 0) wsum[t >> 6] = local;
    __syncthreads();
    if (t == 0) {
        double s = (double)wsum[0] + (double)wsum[1]
                 + (double)wsum[2] + (double)wsum[3];
        atomicAdd(lossAcc, s);
        __threadfence();
        unsigned old = atomicAdd(doneCnt, 1u);
        if (old == 1023u) {
            double tot = atomicAdd(lossAcc, 0.0);
            *loss_out = (float)(tot * (1.25 / 4194304.0));
        }
    }
}

// ----------------------------------------------------------------
extern "C" void kernel_launch(void* const* d_in, const int* in_sizes, int n_in,
                              void* d_out, int out_size, void* d_ws, size_t ws_size,
                              hipStream_t stream) {
    const float* z   = (const float*)d_in[0];
    const float* emb = (const float*)d_in[1];
    float* out = (float*)d_out;
    char* ws = (char*)d_ws;

    unsigned char* Af8 = (unsigned char*)(ws + WS_A8);
    unsigned char* Ef8 = (unsigned char*)(ws + WS_E8);
    unsigned int* keys = (unsigned int*)(ws + WS_KEYS);
    float* zsq      = (float*)(ws + WS_ZSQ);
    float* esq      = (float*)(ws + WS_ESQ);
    double* lossAcc = (double*)(ws + WS_LOSS);
    unsigned* doneCnt = (unsigned*)(ws + WS_CNT);

    prep_kernel<<<768, 256, 0, stream>>>(z, emb, Af8, Ef8, zsq, esq,
                                         lossAcc, doneCnt);
    mfma_score_kernel<<<dim3(64, 128), 256, 0, stream>>>(Af8, Ef8, esq, keys);
    final_kernel<<<1024, 256, 0, stream>>>(keys, z, emb, zsq, esq,
                                           out, out + 4194305, out + 4194304,
                                           lossAcc, doneCnt);
}